// Round 6
// baseline (1325.361 us; speedup 1.0000x reference)
//
#include <hip/hip_runtime.h>

typedef unsigned short bf16_t;
typedef __attribute__((ext_vector_type(8))) __bf16 bf16x8;
typedef __attribute__((ext_vector_type(4))) float f32x4;

__device__ __forceinline__ float bf2f(unsigned v) { return __uint_as_float(v << 16); }
__device__ __forceinline__ bf16_t f2bf(float f) {
  unsigned u = __float_as_uint(f);
  return (bf16_t)((u + 0x7fffu + ((u >> 16) & 1u)) >> 16);
}
__device__ __forceinline__ unsigned pack2(float a, float b) {
  return (unsigned)f2bf(a) | ((unsigned)f2bf(b) << 16);
}

// XCD-chunked grid swizzle: grid = (NT, MT); XCD x owns M-tiles {x, x+8, ...}.
__device__ __forceinline__ void swz_decode(int& mt, int& nt) {
  const int NT = gridDim.x, MT = gridDim.y;
  int lin = blockIdx.y * NT + blockIdx.x;
  if ((MT & 7) == 0 && gridDim.z == 1) {
    int xcd = lin & 7;
    int j = lin >> 3;
    mt = (j / NT) * 8 + xcd;
    nt = j % NT;
  } else {
    mt = blockIdx.y;
    nt = blockIdx.x;
  }
}

// ---------- exclusive scan of name_lens (4096 = 256 threads x 16) ----------
__global__ __launch_bounds__(256) void scan_lens(const int* __restrict__ lens,
                                                 int* __restrict__ offs,
                                                 int* __restrict__ Mact) {
  __shared__ int wsum[4];
  const int t = threadIdx.x;
  int v[16]; int s = 0;
#pragma unroll
  for (int i = 0; i < 16; i++) { v[i] = lens[t * 16 + i]; s += v[i]; }
  const int lane = t & 63, w = t >> 6;
  int x = s;
#pragma unroll
  for (int o = 1; o < 64; o <<= 1) {
    int y = __shfl_up(x, o);
    if (lane >= o) x += y;
  }
  if (lane == 63) wsum[w] = x;
  __syncthreads();
  int base = 0;
  for (int i = 0; i < w; i++) base += wsum[i];
  int run = base + x - s;  // exclusive prefix of this thread's chunk
#pragma unroll
  for (int i = 0; i < 16; i++) { offs[t * 16 + i] = run; run += v[i]; }
  if (t == 255) Mact[0] = run;
}

// ---------- f32 -> bf16 converts ----------
__global__ void cvt_f32_bf16(const float* __restrict__ src, bf16_t* __restrict__ dst, long n4) {
  long i = (long)blockIdx.x * blockDim.x + threadIdx.x;
  if (i >= n4) return;
  float4 v = ((const float4*)src)[i];
  ((uint2*)dst)[i] = make_uint2(pack2(v.x, v.y), pack2(v.z, v.w));
}

// transpose-convert the V slice of enc_in_w: out[l][k][j] = enc_in_w[l][2048+j][k]
__global__ __launch_bounds__(256) void cvt_trans(const float* __restrict__ src,
                                                 bf16_t* __restrict__ dst) {
  __shared__ float tile[32][33];
  const int l = blockIdx.z;
  const int bx = blockIdx.x * 32;  // k (src col)
  const int by = blockIdx.y * 32;  // j (src row within V slice)
  const float* s = src + (size_t)l * 3 * 1024 * 1024 + 2 * 1024 * 1024;
  const int tx = threadIdx.x & 31, ty = threadIdx.x >> 5;
#pragma unroll
  for (int i = 0; i < 32; i += 8)
    tile[ty + i][tx] = s[(size_t)(by + ty + i) * 1024 + bx + tx];
  __syncthreads();
  bf16_t* d = dst + (size_t)l * 1024 * 1024;
#pragma unroll
  for (int i = 0; i < 32; i += 8)
    d[(size_t)(bx + ty + i) * 1024 + by + tx] = f2bf(tile[tx][ty + i]);
}

// combined bias: bc[l][i] = sum_j Wo[l][i][j]*bv[l][j] + bo[l][i]  (f32 inputs)
__global__ __launch_bounds__(256) void bias_comb(const float* __restrict__ enc_out_w,
                                                 const float* __restrict__ enc_in_b,
                                                 const float* __restrict__ enc_out_b,
                                                 float* __restrict__ bc) {
  const int l = blockIdx.y;
  const int wave = threadIdx.x >> 6, lane = threadIdx.x & 63;
  const float* w = enc_out_w + (size_t)l * 1024 * 1024;
  const float* bv = enc_in_b + (size_t)l * 3072 + 2048;
  for (int c = wave; c < 16; c += 4) {
    int i = blockIdx.x * 16 + c;
    const float* wr = w + (size_t)i * 1024;
    float acc = 0.f;
    for (int j = lane; j < 1024; j += 64) acc += wr[j] * bv[j];
#pragma unroll
    for (int o = 32; o > 0; o >>= 1) acc += __shfl_down(acc, o);
    if (lane == 0) bc[(size_t)l * 1024 + i] = acc + enc_out_b[(size_t)l * 1024 + i];
  }
}

// ---------- compacted embedding gather ----------
__global__ void gather_emb_c(const int* __restrict__ tok, const int* __restrict__ lens,
                             const int* __restrict__ offs, const float* __restrict__ wte,
                             bf16_t* __restrict__ emb) {
  long i = (long)blockIdx.x * blockDim.x + threadIdx.x;  // 65536*192
  if (i >= 65536L * 192L) return;
  long nl = i / 192; int cg = (int)(i % 192);
  int n = (int)(nl >> 4), l = (int)(nl & 15);
  if (l >= lens[n]) return;
  long ro = (long)offs[n] + l;
  int t = tok[nl];
  float4 v = *(const float4*)(wte + (long)t * 768 + cg * 4);
  ((uint2*)emb)[ro * 192 + cg] = make_uint2(pack2(v.x, v.y), pack2(v.z, v.w));
}

// ---------- x_feats cast into x[:,0:256] + lens->float ----------
__global__ void xfeat_lenf(const float* __restrict__ xf, const int* __restrict__ lens,
                           bf16_t* __restrict__ x, float* __restrict__ lenf) {
  long i = (long)blockIdx.x * blockDim.x + threadIdx.x;
  if (i < 4096) lenf[i] = (float)lens[i];
  if (i >= 4096L * 64L) return;
  int row = (int)(i >> 6); int c4 = (int)(i & 63) * 4;
  float4 v = *(const float4*)(xf + (long)row * 256 + c4);
  *(uint2*)(x + (long)row * 1024 + c4) = make_uint2(pack2(v.x, v.y), pack2(v.z, v.w));
}

__device__ __forceinline__ void async16(const void* g, void* l) {
  __builtin_amdgcn_global_load_lds((const __attribute__((address_space(1))) void*)g,
                                   (__attribute__((address_space(3))) void*)l, 16, 0, 0);
}

// per-row chunk swizzle for BK=32 (4 x 16B chunks/row)
__device__ __forceinline__ int swz4(int row) { return (row & 3) ^ ((row >> 2) & 3); }

// ---------- FAT GEMM: 256(M)x128(N), wave-tile 128x64 (LDS-throughput fix) ----------
// FLOP per LDS byte: 42.7 vs 32 for 128^2; per-CU 2 blocks -> 1.77x LDS relief.
#define FBM 256
#define FBN 128
#define FBK 32
#define FSB (FBM * FBK + FBN * FBK)  // 12288 elems per buffer

__global__ __launch_bounds__(256, 2) void gemm_fat(
    const bf16_t* __restrict__ A, const bf16_t* __restrict__ W,
    const float* __restrict__ bias, bf16_t* __restrict__ C,
    int K, int ldc, const int* __restrict__ Mp, int mbase) {
  const int m0 = (mbase + blockIdx.y) * FBM;
  if (Mp != nullptr && m0 >= *Mp) return;
  __shared__ __attribute__((aligned(16))) bf16_t smem[2 * FSB];
  const int t = threadIdx.x;
  const int n0 = blockIdx.x * FBN;
  const int lane = t & 63;
  const int wr = t >> 7;           // M half (128 rows each)
  const int wc = (t >> 6) & 1;     // N half (64 cols each)
  const int quad = lane >> 4;
  const int r16 = lane & 15;

  f32x4 acc[8][4] = {};

  // staging: A = 1024 chunks (4/thread), B = 512 (2/thread), XOR-swizzled slots
  int rowA[4], kpA[4]; size_t oA[4];
#pragma unroll
  for (int i = 0; i < 4; i++) {
    int c = t + i * 256;
    rowA[i] = c >> 2;
    kpA[i] = ((c & 3) ^ swz4(rowA[i])) << 3;
    oA[i] = (size_t)(c & ~63) * 8;
  }
  int rowB[2], kpB[2]; size_t oB[2];
#pragma unroll
  for (int i = 0; i < 2; i++) {
    int c = t + i * 256;
    rowB[i] = c >> 2;
    kpB[i] = ((c & 3) ^ swz4(rowB[i])) << 3;
    oB[i] = (size_t)(c & ~63) * 8;
  }
  const bf16_t* Ab = A + (size_t)m0 * K;
  const bf16_t* Wb = W + (size_t)n0 * K;

  auto stage = [&](int b, int k0) {
    bf16_t* As = smem + (size_t)b * FSB;
    bf16_t* Bs = As + FBM * FBK;
#pragma unroll
    for (int i = 0; i < 4; i++) async16(Ab + (size_t)rowA[i] * K + k0 + kpA[i], As + oA[i]);
#pragma unroll
    for (int i = 0; i < 2; i++) async16(Wb + (size_t)rowB[i] * K + k0 + kpB[i], Bs + oB[i]);
  };

  stage(0, 0);
  __syncthreads();
  int cur = 0;
  for (int k0 = 0; k0 < K; k0 += FBK) {
    if (k0 + FBK < K) stage(cur ^ 1, k0 + FBK);
    const bf16_t* As = smem + (size_t)cur * FSB;
    const bf16_t* Bs = As + FBM * FBK;
    bf16x8 af[8], bfr[4];
#pragma unroll
    for (int i = 0; i < 8; i++) {
      int Ra = wr * 128 + i * 16 + r16;
      af[i] = *(const bf16x8*)(As + Ra * FBK + ((quad ^ swz4(Ra)) << 3));
    }
#pragma unroll
    for (int j = 0; j < 4; j++) {
      int Rb = wc * 64 + j * 16 + r16;
      bfr[j] = *(const bf16x8*)(Bs + Rb * FBK + ((quad ^ swz4(Rb)) << 3));
    }
#pragma unroll
    for (int i = 0; i < 8; i++)
#pragma unroll
      for (int j = 0; j < 4; j++)
        acc[i][j] = __builtin_amdgcn_mfma_f32_16x16x32_bf16(af[i], bfr[j], acc[i][j], 0, 0, 0);
    __syncthreads();
    cur ^= 1;
  }

  // ---- coalesced epilogue via LDS: 8 stages of 32 rows x 128 cols ----
  const int ldcs = 136;
  bf16_t* Cs = smem;
#pragma unroll
  for (int s = 0; s < 8; s++) {
    if (wr == (s >> 2)) {
      const int ib = (s & 3) * 2;
#pragma unroll
      for (int i2 = 0; i2 < 2; i2++) {
        const int i = ib + i2;
#pragma unroll
        for (int j = 0; j < 4; j++) {
          int col = wc * 64 + j * 16 + r16;
          float bv = bias ? bias[n0 + col] : 0.0f;
#pragma unroll
          for (int r = 0; r < 4; r++)
            Cs[(i2 * 16 + quad * 4 + r) * ldcs + col] = f2bf(acc[i][j][r] + bv);
        }
      }
    }
    __syncthreads();
    {
      const int rl = t >> 4, cl = (t & 15) * 8;
#pragma unroll
      for (int p = 0; p < 2; p++) {
        int row = rl + p * 16;
        bf16x8 v = *(const bf16x8*)(Cs + row * ldcs + cl);
        *(bf16x8*)(C + (size_t)(m0 + s * 32 + row) * ldc + n0 + cl) = v;
      }
    }
    __syncthreads();
  }
}

// ---------- 128x128 GEMM (encoder/proj): 2-phase dbuf, XOR LDS, XCD swizzle ----------
#define BM 128
#define BN 128
#define BK 32
#define SBT (BM * BK + BN * BK)

template <bool RELU>
__global__ __launch_bounds__(256, 4) void gemm128(
    const bf16_t* __restrict__ A, const bf16_t* __restrict__ W,
    const float* __restrict__ bias, const float* __restrict__ rowscale,
    bf16_t* __restrict__ C, int K, int ldc) {
  int mt, nt;
  swz_decode(mt, nt);
  const int m0 = mt * BM;
  __shared__ __attribute__((aligned(16))) bf16_t smem[2 * SBT];
  const int t = threadIdx.x;
  const int n0 = nt * BN;
  const int lane = t & 63;
  const int wr = t >> 7;
  const int wc = (t >> 6) & 1;
  const int quad = lane >> 4;
  const int r16 = lane & 15;

  f32x4 acc[4][4] = {};

  const int c0 = t, c1 = t + 256;
  const int row0 = c0 >> 2, kp0 = ((c0 & 3) ^ swz4(row0)) << 3;
  const int row1 = c1 >> 2, kp1 = ((c1 & 3) ^ swz4(row1)) << 3;
  const size_t oc0 = (size_t)(c0 & ~63) * 8;
  const size_t oc1 = (size_t)(c1 & ~63) * 8;
  const bf16_t* Ab = A + (size_t)m0 * K;
  const bf16_t* Wb = W + (size_t)n0 * K;

  auto stage = [&](int b, int k0) {
    bf16_t* As = smem + (size_t)b * SBT;
    bf16_t* Bs = As + BM * BK;
    async16(Ab + (size_t)row0 * K + k0 + kp0, As + oc0);
    async16(Ab + (size_t)row1 * K + k0 + kp1, As + oc1);
    async16(Wb + (size_t)row0 * K + k0 + kp0, Bs + oc0);
    async16(Wb + (size_t)row1 * K + k0 + kp1, Bs + oc1);
  };

  stage(0, 0);
  __syncthreads();
  int cur = 0;
  for (int k0 = 0; k0 < K; k0 += BK) {
    if (k0 + BK < K) stage(cur ^ 1, k0 + BK);
    const bf16_t* As = smem + (size_t)cur * SBT;
    const bf16_t* Bs = As + BM * BK;
    bf16x8 af[4], bfr[4];
#pragma unroll
    for (int i = 0; i < 4; i++) {
      int Ra = wr * 64 + i * 16 + r16;
      af[i]  = *(const bf16x8*)(As + Ra * BK + ((quad ^ swz4(Ra)) << 3));
      int Rb = wc * 64 + i * 16 + r16;
      bfr[i] = *(const bf16x8*)(Bs + Rb * BK + ((quad ^ swz4(Rb)) << 3));
    }
#pragma unroll
    for (int i = 0; i < 4; i++)
#pragma unroll
      for (int j = 0; j < 4; j++)
        acc[i][j] = __builtin_amdgcn_mfma_f32_16x16x32_bf16(af[i], bfr[j], acc[i][j], 0, 0, 0);
    __syncthreads();
    cur ^= 1;
  }

  const int ldcs = 136;
  bf16_t* Cs = smem;
#pragma unroll
  for (int s = 0; s < 4; s++) {
    if (wr == (s >> 1)) {
      const int ib = (s & 1) * 2;
#pragma unroll
      for (int i2 = 0; i2 < 2; i2++) {
        const int i = ib + i2;
#pragma unroll
        for (int j = 0; j < 4; j++) {
          int col = wc * 64 + j * 16 + r16;
          float bv = bias ? bias[n0 + col] : 0.0f;
#pragma unroll
          for (int r = 0; r < 4; r++) {
            int grow = m0 + s * 32 + i2 * 16 + quad * 4 + r;
            float sc = rowscale ? rowscale[grow] : 1.0f;
            float v = acc[i][j][r] + bv * sc;
            if (RELU) v = fmaxf(v, 0.0f);
            Cs[(i2 * 16 + quad * 4 + r) * ldcs + col] = f2bf(v);
          }
        }
      }
    }
    __syncthreads();
    {
      const int rl = t >> 4, cl = (t & 15) * 8;
#pragma unroll
      for (int p = 0; p < 2; p++) {
        int row = rl + p * 16;
        bf16x8 v = *(const bf16x8*)(Cs + row * ldcs + cl);
        *(bf16x8*)(C + (size_t)(m0 + s * 32 + row) * ldc + n0 + cl) = v;
      }
    }
    __syncthreads();
  }
}

// ---------- 128x128 batched GEMM for the weight-combine (z = layer) ----------
__global__ __launch_bounds__(256, 4) void gemm_bt(
    const bf16_t* __restrict__ A, const bf16_t* __restrict__ W,
    const float* __restrict__ bias, bf16_t* __restrict__ C,
    int K, int ldc, long sA, long sB, long sC) {
  const int m0 = blockIdx.y * BM;
  __shared__ __attribute__((aligned(16))) bf16_t smem[2 * SBT];
  const int t = threadIdx.x;
  const int n0 = blockIdx.x * BN;
  const int z = blockIdx.z;
  const int lane = t & 63;
  const int wr = t >> 7;
  const int wc = (t >> 6) & 1;
  const int quad = lane >> 4;
  const int r16 = lane & 15;

  f32x4 acc[4][4] = {};

  const int c0 = t, c1 = t + 256;
  const int row0 = c0 >> 2, kp0 = ((c0 & 3) ^ swz4(row0)) << 3;
  const int row1 = c1 >> 2, kp1 = ((c1 & 3) ^ swz4(row1)) << 3;
  const size_t oc0 = (size_t)(c0 & ~63) * 8;
  const size_t oc1 = (size_t)(c1 & ~63) * 8;
  const bf16_t* Ab = A + (size_t)z * sA + (size_t)m0 * K;
  const bf16_t* Wb = W + (size_t)z * sB + (size_t)n0 * K;
  bf16_t* Cb = C + (size_t)z * sC;

  auto stage = [&](int b, int k0) {
    bf16_t* As = smem + (size_t)b * SBT;
    bf16_t* Bs = As + BM * BK;
    async16(Ab + (size_t)row0 * K + k0 + kp0, As + oc0);
    async16(Ab + (size_t)row1 * K + k0 + kp1, As + oc1);
    async16(Wb + (size_t)row0 * K + k0 + kp0, Bs + oc0);
    async16(Wb + (size_t)row1 * K + k0 + kp1, Bs + oc1);
  };

  stage(0, 0);
  __syncthreads();
  int cur = 0;
  for (int k0 = 0; k0 < K; k0 += BK) {
    if (k0 + BK < K) stage(cur ^ 1, k0 + BK);
    const bf16_t* As = smem + (size_t)cur * SBT;
    const bf16_t* Bs = As + BM * BK;
    bf16x8 af[4], bfr[4];
#pragma unroll
    for (int i = 0; i < 4; i++) {
      int Ra = wr * 64 + i * 16 + r16;
      af[i]  = *(const bf16x8*)(As + Ra * BK + ((quad ^ swz4(Ra)) << 3));
      int Rb = wc * 64 + i * 16 + r16;
      bfr[i] = *(const bf16x8*)(Bs + Rb * BK + ((quad ^ swz4(Rb)) << 3));
    }
#pragma unroll
    for (int i = 0; i < 4; i++)
#pragma unroll
      for (int j = 0; j < 4; j++)
        acc[i][j] = __builtin_amdgcn_mfma_f32_16x16x32_bf16(af[i], bfr[j], acc[i][j], 0, 0, 0);
    __syncthreads();
    cur ^= 1;
  }

  const int ldcs = 136;
  bf16_t* Cs = smem;
#pragma unroll
  for (int s = 0; s < 4; s++) {
    if (wr == (s >> 1)) {
      const int ib = (s & 1) * 2;
#pragma unroll
      for (int i2 = 0; i2 < 2; i2++) {
        const int i = ib + i2;
#pragma unroll
        for (int j = 0; j < 4; j++) {
          int col = wc * 64 + j * 16 + r16;
          float bv = bias ? bias[n0 + col] : 0.0f;
#pragma unroll
          for (int r = 0; r < 4; r++)
            Cs[(i2 * 16 + quad * 4 + r) * ldcs + col] = f2bf(acc[i][j][r] + bv);
        }
      }
    }
    __syncthreads();
    {
      const int rl = t >> 4, cl = (t & 15) * 8;
#pragma unroll
      for (int p = 0; p < 2; p++) {
        int row = rl + p * 16;
        bf16x8 v = *(const bf16x8*)(Cs + row * ldcs + cl);
        *(bf16x8*)(Cb + (size_t)(m0 + s * 32 + row) * ldc + n0 + cl) = v;
      }
    }
    __syncthreads();
  }
}

// ---------- name attention on compacted qkv ----------
__global__ __launch_bounds__(64) void attn_name(const bf16_t* __restrict__ qkv,
                                                const int* __restrict__ lens,
                                                const int* __restrict__ offs,
                                                bf16_t* __restrict__ s) {
  const int n = blockIdx.x, h = blockIdx.y;
  const int lane = threadIdx.x;
  __shared__ unsigned short qs[16][208];
  __shared__ unsigned short ks[16][208];
  __shared__ unsigned short vs[16][208];
  __shared__ float ps[16][16];
  __shared__ float wj[16];
  const int len = lens[n];
  const bf16_t* base = qkv + (size_t)offs[n] * 2304 + h * 192;
  for (int g = lane; g < len * 48; g += 64) {
    int row = g / 48, c4 = (g % 48) * 4;
    const bf16_t* p = base + (size_t)row * 2304 + c4;
    uint2 a;
    a = *(const uint2*)p;
    *(unsigned*)&qs[row][c4] = a.x; *(unsigned*)&qs[row][c4 + 2] = a.y;
    a = *(const uint2*)(p + 768);
    *(unsigned*)&ks[row][c4] = a.x; *(unsigned*)&ks[row][c4 + 2] = a.y;
    a = *(const uint2*)(p + 1536);
    *(unsigned*)&vs[row][c4] = a.x; *(unsigned*)&vs[row][c4 + 2] = a.y;
  }
  __syncthreads();
  {
    const int l = lane >> 2, j0 = (lane & 3) * 4;
    float s0 = 0, s1 = 0, s2 = 0, s3 = 0;
    for (int d = 0; d < 192; d++) {
      float q = bf2f(qs[l][d]);
      s0 += q * bf2f(ks[j0 + 0][d]);
      s1 += q * bf2f(ks[j0 + 1][d]);
      s2 += q * bf2f(ks[j0 + 2][d]);
      s3 += q * bf2f(ks[j0 + 3][d]);
    }
    const float sc = 0.07216878f;  // 1/sqrt(192)
    ps[l][j0 + 0] = s0 * sc; ps[l][j0 + 1] = s1 * sc;
    ps[l][j0 + 2] = s2 * sc; ps[l][j0 + 3] = s3 * sc;
  }
  __syncthreads();
  if (lane < 16) {
    float m = -1e30f;
    for (int j = 0; j < len; j++) m = fmaxf(m, ps[lane][j]);
    float sum = 0.f;
    for (int j = 0; j < len; j++) sum += __expf(ps[lane][j] - m);
    float inv = 1.0f / sum;
    for (int j = 0; j < 16; j++) ps[lane][j] = (j < len) ? __expf(ps[lane][j] - m) * inv : 0.0f;
  }
  __syncthreads();
  if (lane < 16) {
    float a = 0.f;
    for (int l2 = 0; l2 < len; l2++) a += ps[l2][lane];
    wj[lane] = a;
  }
  __syncthreads();
  for (int d = lane; d < 192; d += 64) {
    float a = 0.f;
    for (int j = 0; j < len; j++) a += wj[j] * bf2f(vs[j][d]);
    s[(size_t)n * 768 + h * 192 + d] = f2bf(a);
  }
}

// ---------- residual + layernorm (in place on h) ----------
__global__ __launch_bounds__(256) void ln_res(bf16_t* __restrict__ h, const bf16_t* __restrict__ d,
                                              const float* __restrict__ g, const float* __restrict__ b) {
  const int n = blockIdx.x, t = threadIdx.x;
  __shared__ float s1[4], s2[4];
  bf16_t* hr = h + (size_t)n * 1024;
  const bf16_t* dr = d + (size_t)n * 1024;
  float x[4];
  float sum = 0.f, ss = 0.f;
#pragma unroll
  for (int i = 0; i < 4; i++) {
    int c = t + i * 256;
    float v = bf2f(hr[c]) + bf2f(dr[c]);
    x[i] = v; sum += v; ss += v * v;
  }
#pragma unroll
  for (int o = 32; o > 0; o >>= 1) { sum += __shfl_down(sum, o); ss += __shfl_down(ss, o); }
  if ((t & 63) == 0) { s1[t >> 6] = sum; s2[t >> 6] = ss; }
  __syncthreads();
  sum = s1[0] + s1[1] + s1[2] + s1[3];
  ss  = s2[0] + s2[1] + s2[2] + s2[3];
  const float mean = sum * (1.0f / 1024.0f);
  const float var = ss * (1.0f / 1024.0f) - mean * mean;
  const float rstd = rsqrtf(var + 1e-5f);
#pragma unroll
  for (int i = 0; i < 4; i++) {
    int c = t + i * 256;
    hr[c] = f2bf((x[i] - mean) * rstd * g[c] + b[c]);
  }
}

// ---------- classifier head ----------
__global__ __launch_bounds__(256) void cls_head(const bf16_t* __restrict__ h,
                                                const float* __restrict__ cw,
                                                const float* __restrict__ cb,
                                                float* __restrict__ out) {
  const int n = blockIdx.x, t = threadIdx.x, wave = t >> 6, lane = t & 63;
  const bf16_t* hr = h + (size_t)n * 1024;
  for (int c = wave; c < 16; c += 4) {
    const float* wr = cw + c * 1024;
    float acc = 0.f;
    for (int i = lane; i < 1024; i += 64) acc += bf2f(hr[i]) * wr[i];
#pragma unroll
    for (int o = 32; o > 0; o >>= 1) acc += __shfl_down(acc, o);
    if (lane == 0) out[(size_t)n * 16 + c] = acc + cb[c];
  }
}

extern "C" void kernel_launch(void* const* d_in, const int* in_sizes, int n_in,
                              void* d_out, int out_size, void* d_ws, size_t ws_size,
                              hipStream_t stream) {
  (void)in_sizes; (void)n_in; (void)out_size; (void)ws_size;
  const int* name_tokens = (const int*)d_in[0];
  const int* name_lens   = (const int*)d_in[1];
  const float* x_feats   = (const float*)d_in[2];
  const float* wte       = (const float*)d_in[3];
  const float* mha_in_w  = (const float*)d_in[4];
  const float* mha_in_b  = (const float*)d_in[5];
  const float* mha_out_w = (const float*)d_in[6];
  const float* mha_out_b = (const float*)d_in[7];
  const float* bott_w    = (const float*)d_in[8];
  const float* bott_b    = (const float*)d_in[9];
  const float* enc_in_w  = (const float*)d_in[10];
  const float* enc_in_b  = (const float*)d_in[11];
  const float* enc_out_w = (const float*)d_in[12];
  const float* enc_out_b = (const float*)d_in[13];
  const float* enc_ln1_g = (const float*)d_in[14];
  const float* enc_ln1_b = (const float*)d_in[15];
  const float* enc_ln2_g = (const float*)d_in[16];
  const float* enc_ln2_b = (const float*)d_in[17];
  const float* enc_ff1_w = (const float*)d_in[18];
  const float* enc_ff1_b = (const float*)d_in[19];
  const float* enc_ff2_w = (const float*)d_in[20];
  const float* enc_ff2_b = (const float*)d_in[21];
  const float* cls_w     = (const float*)d_in[22];
  const float* cls_b     = (const float*)d_in[23];
  float* out = (float*)d_out;

  char* base = (char*)d_ws;
  size_t off = 0;
  auto alloc = [&](size_t bytes) -> char* {
    char* p = base + off;
    off = (off + bytes + 255) & ~(size_t)255;
    return p;
  };
  bf16_t* w_qkv  = (bf16_t*)alloc((size_t)2304 * 768 * 2);
  bf16_t* w_out  = (bf16_t*)alloc((size_t)768 * 768 * 2);
  bf16_t* w_bott = (bf16_t*)alloc((size_t)1024 * 1024 * 2);
  bf16_t* w_vT   = (bf16_t*)alloc((size_t)4 * 1024 * 1024 * 2);  // transposed V weights
  bf16_t* w_enco = (bf16_t*)alloc((size_t)4 * 1024 * 1024 * 2);
  bf16_t* w_ff1  = (bf16_t*)alloc((size_t)4 * 2048 * 1024 * 2);
  bf16_t* w_ff2  = (bf16_t*)alloc((size_t)4 * 1024 * 2048 * 2);
  float*  lenf   = (float*)alloc((size_t)4096 * 4);
  int*    offs   = (int*)alloc((size_t)4096 * 4);
  int*    Mact   = (int*)alloc((size_t)256);
  char* reuse = alloc((size_t)65536 * 768 * 2);  // emb region, reused after QKV GEMM
  bf16_t* emb = (bf16_t*)reuse;
  bf16_t* s_  = (bf16_t*)reuse;                            // 4096x768
  bf16_t* x_  = (bf16_t*)(reuse + 6291456);                // 4096x1024
  bf16_t* h_  = (bf16_t*)(reuse + 6291456 + 8388608);      // 4096x1024
  bf16_t* v_  = (bf16_t*)(reuse + 6291456 + 2 * 8388608);  // 4096x1024
  bf16_t* a_  = (bf16_t*)(reuse + 6291456 + 3 * 8388608);  // 4096x1024
  bf16_t* f1_ = (bf16_t*)(reuse + 6291456 + 4 * 8388608);  // 4096x2048
  bf16_t* qkv = (bf16_t*)alloc((size_t)65536 * 2304 * 2);
  // fused attention weights live in the qkv region (dead after attn_name)
  bf16_t* wc = (bf16_t*)qkv;                                          // 4x1024x1024 bf16
  float*  bc = (float*)((char*)qkv + (size_t)4 * 1024 * 1024 * 2);    // 4x1024 f32

  dim3 b256(256);
  auto g1 = [](long n4) { return dim3((unsigned)((n4 + 255) / 256)); };

  scan_lens<<<dim3(1), b256, 0, stream>>>(name_lens, offs, Mact);

  // weight converts
  cvt_f32_bf16<<<g1(442368), b256, 0, stream>>>(mha_in_w, w_qkv, 442368L);
  cvt_f32_bf16<<<g1(147456), b256, 0, stream>>>(mha_out_w, w_out, 147456L);
  cvt_f32_bf16<<<g1(262144), b256, 0, stream>>>(bott_w, w_bott, 262144L);
  cvt_trans<<<dim3(32, 32, 4), b256, 0, stream>>>(enc_in_w, w_vT);
  cvt_f32_bf16<<<g1(1048576), b256, 0, stream>>>(enc_out_w, w_enco, 1048576L);
  cvt_f32_bf16<<<g1(2097152), b256, 0, stream>>>(enc_ff1_w, w_ff1, 2097152L);
  cvt_f32_bf16<<<g1(2097152), b256, 0, stream>>>(enc_ff2_w, w_ff2, 2097152L);

  // stage A (compacted rows)
  gather_emb_c<<<dim3(49152), b256, 0, stream>>>(name_tokens, name_lens, offs, wte, emb);
  // QKV GEMM: fat 256x128 tiles, split into 3 M-chunks (visibility + tail overlap)
  gemm_fat<<<dim3(18, 86), b256, 0, stream>>>(emb, w_qkv, mha_in_b, qkv, 768, 2304, Mact, 0);
  gemm_fat<<<dim3(18, 86), b256, 0, stream>>>(emb, w_qkv, mha_in_b, qkv, 768, 2304, Mact, 86);
  gemm_fat<<<dim3(18, 84), b256, 0, stream>>>(emb, w_qkv, mha_in_b, qkv, 768, 2304, Mact, 172);
  xfeat_lenf<<<dim3(1024), b256, 0, stream>>>(x_feats, name_lens, x_, lenf);
  attn_name<<<dim3(4096, 4), dim3(64), 0, stream>>>(qkv, name_lens, offs, s_);

  // qkv region now dead: build fused attention weights Wc_l = Wo_l @ Wv_l (batched)
  gemm_bt<<<dim3(8, 8, 4), b256, 0, stream>>>(
      w_enco, w_vT, (const float*)nullptr, wc, 1024, 1024,
      (long)1024 * 1024, (long)1024 * 1024, (long)1024 * 1024);
  bias_comb<<<dim3(64, 4), b256, 0, stream>>>(enc_out_w, enc_in_b, enc_out_b, bc);

  // projection GEMMs; grid = (NT, MT), XCD-chunked swizzle in-kernel
  gemm128<false><<<dim3(6, 32), b256, 0, stream>>>(s_, w_out, mha_out_b, lenf,
                                                   x_ + 256, 768, 1024);
  gemm128<false><<<dim3(8, 32), b256, 0, stream>>>(x_, w_bott, bott_b,
                                                   (const float*)nullptr, h_, 1024, 1024);
  // encoder layers (seq len 1: attention == single fused linear h @ Wc^T + bc)
  for (int l = 0; l < 4; l++) {
    gemm128<false><<<dim3(8, 32), b256, 0, stream>>>(
        h_, wc + (size_t)l * 1024 * 1024, bc + (size_t)l * 1024,
        (const float*)nullptr, a_, 1024, 1024);
    ln_res<<<dim3(4096), b256, 0, stream>>>(h_, a_, enc_ln1_g + l * 1024, enc_ln1_b + l * 1024);
    gemm128<true><<<dim3(16, 32), b256, 0, stream>>>(
        h_, w_ff1 + (size_t)l * 2048 * 1024, enc_ff1_b + l * 2048,
        (const float*)nullptr, f1_, 1024, 2048);
    gemm128<false><<<dim3(8, 32), b256, 0, stream>>>(
        f1_, w_ff2 + (size_t)l * 1024 * 2048, enc_ff2_b + l * 1024,
        (const float*)nullptr, v_, 2048, 1024);
    ln_res<<<dim3(4096), b256, 0, stream>>>(h_, v_, enc_ln2_g + l * 1024, enc_ln2_b + l * 1024);
  }
  cls_head<<<dim3(4096), b256, 0, stream>>>(h_, cls_w, cls_b, out);
}

// Round 9
// 1096.978 us; speedup vs baseline: 1.2082x; 1.2082x over previous
//
#include <hip/hip_runtime.h>

typedef unsigned short bf16_t;
typedef __attribute__((ext_vector_type(8))) __bf16 bf16x8;
typedef __attribute__((ext_vector_type(4))) float f32x4;

__device__ __forceinline__ float bf2f(unsigned v) { return __uint_as_float(v << 16); }
__device__ __forceinline__ bf16_t f2bf(float f) {
  unsigned u = __float_as_uint(f);
  return (bf16_t)((u + 0x7fffu + ((u >> 16) & 1u)) >> 16);
}
__device__ __forceinline__ unsigned pack2(float a, float b) {
  return (unsigned)f2bf(a) | ((unsigned)f2bf(b) << 16);
}

// ---------- exclusive scan of name_lens (4096 = 256 threads x 16) ----------
__global__ __launch_bounds__(256) void scan_lens(const int* __restrict__ lens,
                                                 int* __restrict__ offs,
                                                 int* __restrict__ Mact) {
  __shared__ int wsum[4];
  const int t = threadIdx.x;
  int v[16]; int s = 0;
#pragma unroll
  for (int i = 0; i < 16; i++) { v[i] = lens[t * 16 + i]; s += v[i]; }
  const int lane = t & 63, w = t >> 6;
  int x = s;
#pragma unroll
  for (int o = 1; o < 64; o <<= 1) {
    int y = __shfl_up(x, o);
    if (lane >= o) x += y;
  }
  if (lane == 63) wsum[w] = x;
  __syncthreads();
  int base = 0;
  for (int i = 0; i < w; i++) base += wsum[i];
  int run = base + x - s;  // exclusive prefix of this thread's chunk
#pragma unroll
  for (int i = 0; i < 16; i++) { offs[t * 16 + i] = run; run += v[i]; }
  if (t == 255) Mact[0] = run;
}

// ---------- f32 -> bf16 converts ----------
__global__ void cvt_f32_bf16(const float* __restrict__ src, bf16_t* __restrict__ dst, long n4) {
  long i = (long)blockIdx.x * blockDim.x + threadIdx.x;
  if (i >= n4) return;
  float4 v = ((const float4*)src)[i];
  ((uint2*)dst)[i] = make_uint2(pack2(v.x, v.y), pack2(v.z, v.w));
}

// transpose-convert the V slice of enc_in_w: out[l][k][j] = enc_in_w[l][2048+j][k]
__global__ __launch_bounds__(256) void cvt_trans(const float* __restrict__ src,
                                                 bf16_t* __restrict__ dst) {
  __shared__ float tile[32][33];
  const int l = blockIdx.z;
  const int bx = blockIdx.x * 32;  // k (src col)
  const int by = blockIdx.y * 32;  // j (src row within V slice)
  const float* s = src + (size_t)l * 3 * 1024 * 1024 + 2 * 1024 * 1024;
  const int tx = threadIdx.x & 31, ty = threadIdx.x >> 5;
#pragma unroll
  for (int i = 0; i < 32; i += 8)
    tile[ty + i][tx] = s[(size_t)(by + ty + i) * 1024 + bx + tx];
  __syncthreads();
  bf16_t* d = dst + (size_t)l * 1024 * 1024;
#pragma unroll
  for (int i = 0; i < 32; i += 8)
    d[(size_t)(bx + ty + i) * 1024 + by + tx] = f2bf(tile[tx][ty + i]);
}

// combined bias: bc[l][i] = sum_j Wo[l][i][j]*bv[l][j] + bo[l][i]  (f32 inputs)
__global__ __launch_bounds__(256) void bias_comb(const float* __restrict__ enc_out_w,
                                                 const float* __restrict__ enc_in_b,
                                                 const float* __restrict__ enc_out_b,
                                                 float* __restrict__ bc) {
  const int l = blockIdx.y;
  const int wave = threadIdx.x >> 6, lane = threadIdx.x & 63;
  const float* w = enc_out_w + (size_t)l * 1024 * 1024;
  const float* bv = enc_in_b + (size_t)l * 3072 + 2048;
  for (int c = wave; c < 16; c += 4) {
    int i = blockIdx.x * 16 + c;
    const float* wr = w + (size_t)i * 1024;
    float acc = 0.f;
    for (int j = lane; j < 1024; j += 64) acc += wr[j] * bv[j];
#pragma unroll
    for (int o = 32; o > 0; o >>= 1) acc += __shfl_down(acc, o);
    if (lane == 0) bc[(size_t)l * 1024 + i] = acc + enc_out_b[(size_t)l * 1024 + i];
  }
}

// ---------- compacted embedding gather ----------
__global__ void gather_emb_c(const int* __restrict__ tok, const int* __restrict__ lens,
                             const int* __restrict__ offs, const float* __restrict__ wte,
                             bf16_t* __restrict__ emb) {
  long i = (long)blockIdx.x * blockDim.x + threadIdx.x;  // 65536*192
  if (i >= 65536L * 192L) return;
  long nl = i / 192; int cg = (int)(i % 192);
  int n = (int)(nl >> 4), l = (int)(nl & 15);
  if (l >= lens[n]) return;
  long ro = (long)offs[n] + l;
  int t = tok[nl];
  float4 v = *(const float4*)(wte + (long)t * 768 + cg * 4);
  ((uint2*)emb)[ro * 192 + cg] = make_uint2(pack2(v.x, v.y), pack2(v.z, v.w));
}

// ---------- x_feats cast into x[:,0:256] + lens->float ----------
__global__ void xfeat_lenf(const float* __restrict__ xf, const int* __restrict__ lens,
                           bf16_t* __restrict__ x, float* __restrict__ lenf) {
  long i = (long)blockIdx.x * blockDim.x + threadIdx.x;
  if (i < 4096) lenf[i] = (float)lens[i];
  if (i >= 4096L * 64L) return;
  int row = (int)(i >> 6); int c4 = (int)(i & 63) * 4;
  float4 v = *(const float4*)(xf + (long)row * 256 + c4);
  *(uint2*)(x + (long)row * 1024 + c4) = make_uint2(pack2(v.x, v.y), pack2(v.z, v.w));
}

__device__ __forceinline__ void async16(const void* g, void* l) {
  __builtin_amdgcn_global_load_lds((const __attribute__((address_space(1))) void*)g,
                                   (__attribute__((address_space(3))) void*)l, 16, 0, 0);
}

// ---------- 128x128 MFMA GEMM (large-M, batched, 2-phase dbuf) ----------
#define BM 128
#define BN 128
#define BK 32
#define SBT (BM * BK + BN * BK)  // 8192 bf16 elems per buffer

__global__ __launch_bounds__(256, 2) void gemm_bt(
    const bf16_t* __restrict__ A, const bf16_t* __restrict__ W,
    const float* __restrict__ bias, bf16_t* __restrict__ C,
    int K, int ldc, const int* __restrict__ Mp,
    long sA, long sB, long sC) {
  const int m0 = blockIdx.y * BM;
  if (Mp != nullptr && m0 >= *Mp) return;  // compaction early-exit (block-uniform)
  __shared__ __attribute__((aligned(16))) bf16_t smem[2 * SBT];
  const int t = threadIdx.x;
  const int n0 = blockIdx.x * BN;
  const int z = blockIdx.z;
  const int lane = t & 63;
  const int wr = t >> 7;
  const int wc = (t >> 6) & 1;
  const int quad = lane >> 4;
  const int r16 = lane & 15;

  f32x4 acc[4][4] = {};

  const int c0 = t, c1 = t + 256;
  const int row0 = c0 >> 2, kp0 = (c0 & 3) << 3;
  const int row1 = c1 >> 2, kp1 = (c1 & 3) << 3;
  const size_t oc0 = (size_t)(c0 & ~63) * 8;
  const size_t oc1 = (size_t)(c1 & ~63) * 8;
  const bf16_t* Ab = A + (size_t)z * sA + (size_t)m0 * K;
  const bf16_t* Wb = W + (size_t)z * sB + (size_t)n0 * K;
  bf16_t* Cb = C + (size_t)z * sC;

  auto stage = [&](int b, int k0) {
    bf16_t* As = smem + (size_t)b * SBT;
    bf16_t* Bs = As + BM * BK;
    async16(Ab + (size_t)row0 * K + k0 + kp0, As + oc0);
    async16(Ab + (size_t)row1 * K + k0 + kp1, As + oc1);
    async16(Wb + (size_t)row0 * K + k0 + kp0, Bs + oc0);
    async16(Wb + (size_t)row1 * K + k0 + kp1, Bs + oc1);
  };

  stage(0, 0);
  __syncthreads();
  int cur = 0;
  for (int k0 = 0; k0 < K; k0 += BK) {
    if (k0 + BK < K) stage(cur ^ 1, k0 + BK);
    const bf16_t* As = smem + (size_t)cur * SBT;
    const bf16_t* Bs = As + BM * BK;
    bf16x8 af[4], bfr[4];
#pragma unroll
    for (int i = 0; i < 4; i++) {
      af[i]  = *(const bf16x8*)(As + (wr * 64 + i * 16 + r16) * BK + quad * 8);
      bfr[i] = *(const bf16x8*)(Bs + (wc * 64 + i * 16 + r16) * BK + quad * 8);
    }
#pragma unroll
    for (int i = 0; i < 4; i++)
#pragma unroll
      for (int j = 0; j < 4; j++)
        acc[i][j] = __builtin_amdgcn_mfma_f32_16x16x32_bf16(af[i], bfr[j], acc[i][j], 0, 0, 0);
    __syncthreads();
    cur ^= 1;
  }

  // ---- coalesced epilogue via LDS ----
  const int ldcs = 136;  // +8 pad
  bf16_t* Cs = smem;
#pragma unroll
  for (int s = 0; s < 4; s++) {
    if (wr == (s >> 1)) {
      const int ib = (s & 1) * 2;
#pragma unroll
      for (int i2 = 0; i2 < 2; i2++) {
        const int i = ib + i2;
#pragma unroll
        for (int j = 0; j < 4; j++) {
          int col = wc * 64 + j * 16 + r16;
          float bv = bias ? bias[n0 + col] : 0.0f;
#pragma unroll
          for (int r = 0; r < 4; r++)
            Cs[(i2 * 16 + quad * 4 + r) * ldcs + col] = f2bf(acc[i][j][r] + bv);
        }
      }
    }
    __syncthreads();
    {
      const int rl = t >> 4, cl = (t & 15) * 8;
#pragma unroll
      for (int p = 0; p < 2; p++) {
        int row = rl + p * 16;
        bf16x8 v = *(const bf16x8*)(Cs + row * ldcs + cl);
        *(bf16x8*)(Cb + (size_t)(m0 + s * 32 + row) * ldc + n0 + cl) = v;
      }
    }
    __syncthreads();
  }
}

// ---------- 128(M)x64(N) MFMA GEMM, XOR-swizzled LDS, M-major grid (r3-best) ----------
template <bool RELU>
__global__ __launch_bounds__(256, 4) void gemm128x64(
    const bf16_t* __restrict__ A, const bf16_t* __restrict__ W,
    const float* __restrict__ bias, const float* __restrict__ rowscale,
    bf16_t* __restrict__ C, int K, int ldc) {
  __shared__ __attribute__((aligned(16))) bf16_t smem[128 * 64 + 64 * 64];
  bf16_t* As = smem;
  bf16_t* Bs = smem + 128 * 64;
  const int t = threadIdx.x;
  const int m0 = blockIdx.x * 128, n0 = blockIdx.y * 64;
  const int lane = t & 63, w = t >> 6;  // wave w owns M-rows [w*32, w*32+32)
  const int quad = lane >> 4, r16 = lane & 15;
  f32x4 acc[2][4] = {};
  int rowA[4], kpA[4];
  bf16_t* lA[4];
#pragma unroll
  for (int i = 0; i < 4; i++) {
    int c = t + i * 256;
    rowA[i] = c >> 3;
    kpA[i] = ((c & 7) ^ (rowA[i] & 7)) << 3;
    lA[i] = As + (size_t)(c & ~63) * 8;
  }
  int rowB[2], kpB[2];
  bf16_t* lB[2];
#pragma unroll
  for (int i = 0; i < 2; i++) {
    int c = t + i * 256;
    rowB[i] = c >> 3;
    kpB[i] = ((c & 7) ^ (rowB[i] & 7)) << 3;
    lB[i] = Bs + (size_t)(c & ~63) * 8;
  }
  const bf16_t* Ab = A + (size_t)m0 * K;
  const bf16_t* Wb = W + (size_t)n0 * K;

  for (int k0 = 0; k0 < K; k0 += 64) {
    __syncthreads();
#pragma unroll
    for (int i = 0; i < 4; i++) async16(Ab + (size_t)rowA[i] * K + k0 + kpA[i], lA[i]);
#pragma unroll
    for (int i = 0; i < 2; i++) async16(Wb + (size_t)rowB[i] * K + k0 + kpB[i], lB[i]);
    __syncthreads();
#pragma unroll
    for (int kk8 = 0; kk8 < 8; kk8 += 4) {
      bf16x8 af[2], bfr[4];
#pragma unroll
      for (int i = 0; i < 2; i++) {
        int Ra = w * 32 + i * 16 + r16;
        af[i] = *(const bf16x8*)(As + Ra * 64 + (((kk8 + quad) ^ (Ra & 7)) << 3));
      }
#pragma unroll
      for (int j = 0; j < 4; j++) {
        int Rb = j * 16 + r16;
        bfr[j] = *(const bf16x8*)(Bs + Rb * 64 + (((kk8 + quad) ^ (Rb & 7)) << 3));
      }
#pragma unroll
      for (int i = 0; i < 2; i++)
#pragma unroll
        for (int j = 0; j < 4; j++)
          acc[i][j] = __builtin_amdgcn_mfma_f32_16x16x32_bf16(af[i], bfr[j], acc[i][j], 0, 0, 0);
    }
  }

  // ---- coalesced epilogue via LDS ----
  __syncthreads();
  const int ldcs = 72;  // +8 pad
  bf16_t* Cs = smem;
#pragma unroll
  for (int i = 0; i < 2; i++) {
#pragma unroll
    for (int j = 0; j < 4; j++) {
      int col = j * 16 + r16;
      float bv = bias ? bias[n0 + col] : 0.0f;
#pragma unroll
      for (int r = 0; r < 4; r++) {
        int row = w * 32 + i * 16 + quad * 4 + r;
        float sc = rowscale ? rowscale[m0 + row] : 1.0f;
        float v = acc[i][j][r] + bv * sc;
        if (RELU) v = fmaxf(v, 0.0f);
        Cs[row * ldcs + col] = f2bf(v);
      }
    }
  }
  __syncthreads();
  {
    const int rl = t >> 3, cl = (t & 7) * 8;
#pragma unroll
    for (int p = 0; p < 4; p++) {
      int row = rl + p * 32;
      bf16x8 v = *(const bf16x8*)(Cs + row * ldcs + cl);
      *(bf16x8*)(C + (size_t)(m0 + row) * ldc + n0 + cl) = v;
    }
  }
}

// ---------- name attention: MFMA QK^T + in-register softmax (wave = head) ----------
// S[l][j] = q_l . k_j / sqrt(192) via 6x mfma_16x16x32; C-layout: row=quad*4+r, col=r16.
// Query-sum trick: wj[j] = sum_{l<len} softmax(S)[l][j]; out[d] = sum_j wj[j] V[j][d].
__global__ __launch_bounds__(256) void attn_name(const bf16_t* __restrict__ qkv,
                                                 const int* __restrict__ lens,
                                                 const int* __restrict__ offs,
                                                 bf16_t* __restrict__ s) {
  const int n = blockIdx.x;
  const int h = threadIdx.x >> 6;       // wave = head
  const int lane = threadIdx.x & 63;
  const int quad = lane >> 4, r16 = lane & 15;
  __shared__ bf16_t vs[4][16][200];     // pitch 200: rows 4 banks apart -> 2-way max (free)
  __shared__ float wjs[4][16];
  const int len = lens[n];
  const size_t rbase = (size_t)offs[n] * 2304 + h * 192;
  const bf16_t* qp = qkv + rbase;
  const bf16_t* kp = qkv + rbase + 768;
  const bf16_t* vp = qkv + rbase + 1536;

  // issue V staging loads early (global -> reg); rows clamped (len >= 1)
  const int vrow = lane >> 2, vc = lane & 3;
  const int vrr = (vrow < len) ? vrow : 0;
  uint2 vbuf[12];
#pragma unroll
  for (int i = 0; i < 12; i++)
    vbuf[i] = *(const uint2*)(vp + (size_t)vrr * 2304 + (vc + i * 4) * 4);

  // QK^T: fragments straight from global (rows clamped to avoid OOB)
  const int rr = (r16 < len) ? r16 : 0;
  f32x4 acc = {};
#pragma unroll
  for (int ks = 0; ks < 6; ks++) {
    bf16x8 aq = *(const bf16x8*)(qp + (size_t)rr * 2304 + ks * 32 + quad * 8);
    bf16x8 bk = *(const bf16x8*)(kp + (size_t)rr * 2304 + ks * 32 + quad * 8);
    acc = __builtin_amdgcn_mfma_f32_16x16x32_bf16(aq, bk, acc, 0, 0, 0);
  }

  // masked in-register softmax + query-sum
  const float sc = 0.07216878f;  // 1/sqrt(192)
  float p[4];
#pragma unroll
  for (int r = 0; r < 4; r++) {
    float x = (r16 < len) ? acc[r] * sc : -1e30f;  // col mask
    float m = x;
    m = fmaxf(m, __shfl_xor(m, 1));
    m = fmaxf(m, __shfl_xor(m, 2));
    m = fmaxf(m, __shfl_xor(m, 4));
    m = fmaxf(m, __shfl_xor(m, 8));
    float e = __expf(x - m);
    float sum = e;
    sum += __shfl_xor(sum, 1);
    sum += __shfl_xor(sum, 2);
    sum += __shfl_xor(sum, 4);
    sum += __shfl_xor(sum, 8);
    p[r] = ((quad * 4 + r) < len) ? e / sum : 0.0f;  // row mask (select, not mul)
  }
  float wj = p[0] + p[1] + p[2] + p[3];
  wj += __shfl_xor(wj, 16);
  wj += __shfl_xor(wj, 32);
  if (quad == 0) wjs[h][r16] = wj;

  // commit V to LDS
  if (vrow < len) {
#pragma unroll
    for (int i = 0; i < 12; i++)
      *(uint2*)&vs[h][vrow][(vc + i * 4) * 4] = vbuf[i];
  }
  __syncthreads();

  // PV: d = lane + 64c
  float o0 = 0.f, o1 = 0.f, o2 = 0.f;
  for (int j = 0; j < len; j++) {
    float w = wjs[h][j];
    o0 += w * bf2f(vs[h][j][lane]);
    o1 += w * bf2f(vs[h][j][lane + 64]);
    o2 += w * bf2f(vs[h][j][lane + 128]);
  }
  bf16_t* op = s + (size_t)n * 768 + h * 192;
  op[lane] = f2bf(o0);
  op[lane + 64] = f2bf(o1);
  op[lane + 128] = f2bf(o2);
}

// ---------- residual + layernorm (in place on h) ----------
__global__ __launch_bounds__(256) void ln_res(bf16_t* __restrict__ h, const bf16_t* __restrict__ d,
                                              const float* __restrict__ g, const float* __restrict__ b) {
  const int n = blockIdx.x, t = threadIdx.x;
  __shared__ float s1[4], s2[4];
  bf16_t* hr = h + (size_t)n * 1024;
  const bf16_t* dr = d + (size_t)n * 1024;
  float x[4];
  float sum = 0.f, ss = 0.f;
#pragma unroll
  for (int i = 0; i < 4; i++) {
    int c = t + i * 256;
    float v = bf2f(hr[c]) + bf2f(dr[c]);
    x[i] = v; sum += v; ss += v * v;
  }
#pragma unroll
  for (int o = 32; o > 0; o >>= 1) { sum += __shfl_down(sum, o); ss += __shfl_down(ss, o); }
  if ((t & 63) == 0) { s1[t >> 6] = sum; s2[t >> 6] = ss; }
  __syncthreads();
  sum = s1[0] + s1[1] + s1[2] + s1[3];
  ss  = s2[0] + s2[1] + s2[2] + s2[3];
  const float mean = sum * (1.0f / 1024.0f);
  const float var = ss * (1.0f / 1024.0f) - mean * mean;
  const float rstd = rsqrtf(var + 1e-5f);
#pragma unroll
  for (int i = 0; i < 4; i++) {
    int c = t + i * 256;
    hr[c] = f2bf((x[i] - mean) * rstd * g[c] + b[c]);
  }
}

// ---------- classifier head ----------
__global__ __launch_bounds__(256) void cls_head(const bf16_t* __restrict__ h,
                                                const float* __restrict__ cw,
                                                const float* __restrict__ cb,
                                                float* __restrict__ out) {
  const int n = blockIdx.x, t = threadIdx.x, wave = t >> 6, lane = t & 63;
  const bf16_t* hr = h + (size_t)n * 1024;
  for (int c = wave; c < 16; c += 4) {
    const float* wr = cw + c * 1024;
    float acc = 0.f;
    for (int i = lane; i < 1024; i += 64) acc += bf2f(hr[i]) * wr[i];
#pragma unroll
    for (int o = 32; o > 0; o >>= 1) acc += __shfl_down(acc, o);
    if (lane == 0) out[(size_t)n * 16 + c] = acc + cb[c];
  }
}

extern "C" void kernel_launch(void* const* d_in, const int* in_sizes, int n_in,
                              void* d_out, int out_size, void* d_ws, size_t ws_size,
                              hipStream_t stream) {
  (void)in_sizes; (void)n_in; (void)out_size; (void)ws_size;
  const int* name_tokens = (const int*)d_in[0];
  const int* name_lens   = (const int*)d_in[1];
  const float* x_feats   = (const float*)d_in[2];
  const float* wte       = (const float*)d_in[3];
  const float* mha_in_w  = (const float*)d_in[4];
  const float* mha_in_b  = (const float*)d_in[5];
  const float* mha_out_w = (const float*)d_in[6];
  const float* mha_out_b = (const float*)d_in[7];
  const float* bott_w    = (const float*)d_in[8];
  const float* bott_b    = (const float*)d_in[9];
  const float* enc_in_w  = (const float*)d_in[10];
  const float* enc_in_b  = (const float*)d_in[11];
  const float* enc_out_w = (const float*)d_in[12];
  const float* enc_out_b = (const float*)d_in[13];
  const float* enc_ln1_g = (const float*)d_in[14];
  const float* enc_ln1_b = (const float*)d_in[15];
  const float* enc_ln2_g = (const float*)d_in[16];
  const float* enc_ln2_b = (const float*)d_in[17];
  const float* enc_ff1_w = (const float*)d_in[18];
  const float* enc_ff1_b = (const float*)d_in[19];
  const float* enc_ff2_w = (const float*)d_in[20];
  const float* enc_ff2_b = (const float*)d_in[21];
  const float* cls_w     = (const float*)d_in[22];
  const float* cls_b     = (const float*)d_in[23];
  float* out = (float*)d_out;

  char* base = (char*)d_ws;
  size_t off = 0;
  auto alloc = [&](size_t bytes) -> char* {
    char* p = base + off;
    off = (off + bytes + 255) & ~(size_t)255;
    return p;
  };
  bf16_t* w_qkv  = (bf16_t*)alloc((size_t)2304 * 768 * 2);
  bf16_t* w_out  = (bf16_t*)alloc((size_t)768 * 768 * 2);
  bf16_t* w_bott = (bf16_t*)alloc((size_t)1024 * 1024 * 2);
  bf16_t* w_vT   = (bf16_t*)alloc((size_t)4 * 1024 * 1024 * 2);  // transposed V weights
  bf16_t* w_enco = (bf16_t*)alloc((size_t)4 * 1024 * 1024 * 2);
  bf16_t* w_ff1  = (bf16_t*)alloc((size_t)4 * 2048 * 1024 * 2);
  bf16_t* w_ff2  = (bf16_t*)alloc((size_t)4 * 1024 * 2048 * 2);
  float*  lenf   = (float*)alloc((size_t)4096 * 4);
  int*    offs   = (int*)alloc((size_t)4096 * 4);
  int*    Mact   = (int*)alloc((size_t)256);
  char* reuse = alloc((size_t)65536 * 768 * 2);  // emb region, reused after QKV GEMM
  bf16_t* emb = (bf16_t*)reuse;
  bf16_t* s_  = (bf16_t*)reuse;                            // 4096x768
  bf16_t* x_  = (bf16_t*)(reuse + 6291456);                // 4096x1024
  bf16_t* h_  = (bf16_t*)(reuse + 6291456 + 8388608);      // 4096x1024
  bf16_t* v_  = (bf16_t*)(reuse + 6291456 + 2 * 8388608);  // 4096x1024
  bf16_t* a_  = (bf16_t*)(reuse + 6291456 + 3 * 8388608);  // 4096x1024
  bf16_t* f1_ = (bf16_t*)(reuse + 6291456 + 4 * 8388608);  // 4096x2048
  bf16_t* qkv = (bf16_t*)alloc((size_t)65536 * 2304 * 2);
  // fused attention weights live in the qkv region (dead after attn_name)
  bf16_t* wc = (bf16_t*)qkv;                                          // 4x1024x1024 bf16
  float*  bc = (float*)((char*)qkv + (size_t)4 * 1024 * 1024 * 2);    // 4x1024 f32

  dim3 b256(256);
  auto g1 = [](long n4) { return dim3((unsigned)((n4 + 255) / 256)); };

  scan_lens<<<dim3(1), b256, 0, stream>>>(name_lens, offs, Mact);

  // weight converts
  cvt_f32_bf16<<<g1(442368), b256, 0, stream>>>(mha_in_w, w_qkv, 442368L);
  cvt_f32_bf16<<<g1(147456), b256, 0, stream>>>(mha_out_w, w_out, 147456L);
  cvt_f32_bf16<<<g1(262144), b256, 0, stream>>>(bott_w, w_bott, 262144L);
  cvt_trans<<<dim3(32, 32, 4), b256, 0, stream>>>(enc_in_w, w_vT);
  cvt_f32_bf16<<<g1(1048576), b256, 0, stream>>>(enc_out_w, w_enco, 1048576L);
  cvt_f32_bf16<<<g1(2097152), b256, 0, stream>>>(enc_ff1_w, w_ff1, 2097152L);
  cvt_f32_bf16<<<g1(2097152), b256, 0, stream>>>(enc_ff2_w, w_ff2, 2097152L);

  // stage A (compacted rows)
  gather_emb_c<<<dim3(49152), b256, 0, stream>>>(name_tokens, name_lens, offs, wte, emb);
  gemm_bt<<<dim3(18, 512), b256, 0, stream>>>(emb, w_qkv, mha_in_b, qkv, 768, 2304, Mact,
                                              0L, 0L, 0L);
  xfeat_lenf<<<dim3(1024), b256, 0, stream>>>(x_feats, name_lens, x_, lenf);
  attn_name<<<dim3(4096), b256, 0, stream>>>(qkv, name_lens, offs, s_);

  // qkv region now dead: build fused attention weights Wc_l = Wo_l @ Wv_l (batched)
  gemm_bt<<<dim3(8, 8, 4), b256, 0, stream>>>(
      w_enco, w_vT, (const float*)nullptr, wc, 1024, 1024, (const int*)nullptr,
      (long)1024 * 1024, (long)1024 * 1024, (long)1024 * 1024);
  bias_comb<<<dim3(64, 4), b256, 0, stream>>>(enc_out_w, enc_in_b, enc_out_b, bc);

  // projection GEMMs (M-major grids: blockIdx.x = M-tile)
  gemm128x64<false><<<dim3(32, 12), b256, 0, stream>>>(s_, w_out, mha_out_b, lenf,
                                                       x_ + 256, 768, 1024);
  gemm128x64<false><<<dim3(32, 16), b256, 0, stream>>>(x_, w_bott, bott_b,
                                                       (const float*)nullptr, h_, 1024, 1024);
  // encoder layers (seq len 1: attention == single fused linear h @ Wc^T + bc)
  for (int l = 0; l < 4; l++) {
    gemm128x64<false><<<dim3(32, 16), b256, 0, stream>>>(
        h_, wc + (size_t)l * 1024 * 1024, bc + (size_t)l * 1024,
        (const float*)nullptr, a_, 1024, 1024);
    ln_res<<<dim3(4096), b256, 0, stream>>>(h_, a_, enc_ln1_g + l * 1024, enc_ln1_b + l * 1024);
    gemm128x64<true><<<dim3(32, 32), b256, 0, stream>>>(
        h_, w_ff1 + (size_t)l * 2048 * 1024, enc_ff1_b + l * 2048,
        (const float*)nullptr, f1_, 1024, 2048);
    gemm128x64<false><<<dim3(32, 16), b256, 0, stream>>>(
        f1_, w_ff2 + (size_t)l * 1024 * 2048, enc_ff2_b + l * 1024,
        (const float*)nullptr, v_, 2048, 1024);
    ln_res<<<dim3(4096), b256, 0, stream>>>(h_, v_, enc_ln2_g + l * 1024, enc_ln2_b + l * 1024);
  }
  cls_head<<<dim3(4096), b256, 0, stream>>>(h_, cls_w, cls_b, out);
}